// Round 3
// baseline (1595.575 us; speedup 1.0000x reference)
//
#include <hip/hip_runtime.h>
#include <hip/hip_bf16.h>
#include <cstdint>

#define B_ 256
#define D_ 128
#define T_ 512
#define H_ 256
#define C_ 10

using f32x4 = __attribute__((ext_vector_type(4))) float;
using s16x8 = __attribute__((ext_vector_type(8))) short;

__device__ __forceinline__ unsigned short f2bf(float f) {
    union { float f; uint32_t u; } a; a.f = f;
    uint32_t u = a.u;
    uint32_t r = (u + 0x7fffu + ((u >> 16) & 1u)) >> 16;   // RNE
    return (unsigned short)r;
}

__device__ __forceinline__ float sigm(float v) { return 1.0f / (1.0f + __expf(-v)); }

// lgkm-only barrier: orders LDS traffic without draining in-flight global
// stores/loads (vmcnt). Global-load consumption is ordered per-thread by
// compiler-inserted vmcnt waits; nothing inter-thread flows through vmem
// inside a block.
__device__ __forceinline__ void bar_lds() {
    asm volatile("s_waitcnt lgkmcnt(0)\n\ts_barrier" ::: "memory");
}

// ---------------------------------------------------------------------------
// Kernel 1: transpose x [B][D][T] f32  ->  xt [T][B][D] bf16
// ---------------------------------------------------------------------------
__global__ void xt_kernel(const float* __restrict__ x, unsigned short* __restrict__ xt) {
    __shared__ unsigned short tile[128][66];
    const int b  = blockIdx.x >> 3;
    const int t0 = (blockIdx.x & 7) << 6;
    const int tid = threadIdx.x;
    const int j  = tid & 63;
    const int dq = tid >> 6;

#pragma unroll
    for (int it = 0; it < 32; ++it) {
        int d = it * 4 + dq;
        tile[d][j] = f2bf(x[(size_t)(b * D_ + d) * T_ + t0 + j]);
    }
    __syncthreads();

    uint32_t* xt32 = (uint32_t*)xt;
#pragma unroll
    for (int it = 0; it < 16; ++it) {
        int tl = it * 4 + dq;
        int dp = j;
        uint32_t lo = tile[2 * dp][tl];
        uint32_t hi = tile[2 * dp + 1][tl];
        xt32[(size_t)((t0 + tl) * B_ + b) * (D_ / 2) + dp] = lo | (hi << 16);
    }
}

// ---------------------------------------------------------------------------
// Kernel 2: persistent LSTM recurrence + fused output projection.
// 256 blocks = 16 batch-chunks (bc) x 16 H-slices (hc), 256 threads (4 waves).
// Wave w = gate w. Per step: [16 x 384] @ [384 x 64] via mfma_16x16x32_bf16.
// h exchange: each u64 word = [tag(t) in high 32 | 2 bf16 units in low 32].
// Consumers poll the data words directly (retry until tag == t-1): ONE MALL
// round trip per step instead of three (no flag, no producer drain).
// Double-buffered by step parity. Initial 0xAA poison never matches a tag.
// ---------------------------------------------------------------------------
__global__ void __launch_bounds__(256) lstm_kernel(
    const float* __restrict__ Wgx, const float* __restrict__ Wix,
    const float* __restrict__ Wfx, const float* __restrict__ Wox,
    const float* __restrict__ Wgh, const float* __restrict__ Wih,
    const float* __restrict__ Wfh, const float* __restrict__ Woh,
    const float* __restrict__ bg,  const float* __restrict__ bi,
    const float* __restrict__ bf2, const float* __restrict__ bo,
    const unsigned short* __restrict__ xt,
    uint64_t* __restrict__ hbuf,
    const float* __restrict__ Wph, const float* __restrict__ bp,
    float* __restrict__ out)
{
    __shared__ __align__(16) unsigned short Wh_s[4][16][264];
    __shared__ __align__(16) unsigned short Wx_s[4][16][136];
    __shared__ __align__(16) unsigned short h_s[16][264];
    __shared__ __align__(16) unsigned short x_s[16][136];
    __shared__ float pre_s[4][16][17];
    __shared__ float bias_s[4][16];

    const int tid  = threadIdx.x;
    const int bc   = blockIdx.x & 15;
    const int hc   = blockIdx.x >> 4;
    const int wave = tid >> 6;
    const int lane = tid & 63;
    const int mrow = lane & 15;
    const int quad = lane >> 4;

    const float* Wh[4] = {Wgh, Wih, Wfh, Woh};
    const float* Wx[4] = {Wgx, Wix, Wfx, Wox};
    const float* bias[4] = {bg, bi, bf2, bo};

#pragma unroll
    for (int g = 0; g < 4; ++g) {
        for (int it = 0; it < 16; ++it) {
            int idx = it * 256 + tid;
            int k = idx >> 4, c = idx & 15;
            Wh_s[g][c][k] = f2bf(Wh[g][(size_t)k * H_ + hc * 16 + c]);
        }
        for (int it = 0; it < 8; ++it) {
            int idx = it * 256 + tid;
            int k = idx >> 4, c = idx & 15;
            Wx_s[g][c][k] = f2bf(Wx[g][(size_t)k * H_ + hc * 16 + c]);
        }
    }
    if (tid < 64) bias_s[tid >> 4][tid & 15] = bias[tid >> 4][hc * 16 + (tid & 15)];
    __syncthreads();

    const int b_l = tid >> 4;
    const int u_l = tid & 15;
    float c_st = 0.0f, h_st = 0.0f;

    // per-thread poll targets: same word-column kp for all 8 rows
    const int kp    = tid & 127;            // u64 word index within a row
    const int rbase = tid >> 7;             // 0 or 1

    // prefetch x for t=0
    uint4 xv = *(const uint4*)(xt + ((size_t)(bc * 16 + b_l) * D_ + u_l * 8));

    for (int t = 0; t < T_; ++t) {
        // issue h(t-1) polls immediately (overlap with x path below)
        uint64_t hv[8];
        const uint64_t* src = hbuf + (size_t)((t - 1) & 1) * (B_ * (H_ / 2));
        if (t > 0) {
#pragma unroll
            for (int i = 0; i < 8; ++i) {
                int row = i * 2 + rbase;
                hv[i] = __hip_atomic_load(&src[(size_t)(bc * 16 + row) * (H_ / 2) + kp],
                                          __ATOMIC_RELAXED, __HIP_MEMORY_SCOPE_AGENT);
            }
        }

        // publish this step's x into LDS (xv prefetched last iteration)
        *(uint4*)&x_s[b_l][u_l * 8] = xv;
        bar_lds();   // A: x_s visible

        // prefetch next step's x
        if (t + 1 < T_)
            xv = *(const uint4*)(xt + ((size_t)((t + 1) * B_ + bc * 16 + b_l) * D_ + u_l * 8));

        // x-projection MFMAs (independent of h -> overlaps the poll latency)
        f32x4 accx = {0.f, 0.f, 0.f, 0.f};
#pragma unroll
        for (int kk = 0; kk < 4; ++kk) {
            s16x8 a  = *(const s16x8*)&x_s[mrow][kk * 32 + quad * 8];
            s16x8 bb = *(const s16x8*)&Wx_s[wave][mrow][kk * 32 + quad * 8];
            accx = __builtin_amdgcn_mfma_f32_16x16x32_bf16(a, bb, accx, 0, 0, 0);
        }

        if (t > 0) {
            const uint32_t want = (uint32_t)(t - 1);
            while (true) {
                bool ok = true;
#pragma unroll
                for (int i = 0; i < 8; ++i)
                    ok &= ((uint32_t)(hv[i] >> 32) == want);
                if (ok) break;
#pragma unroll
                for (int i = 0; i < 8; ++i) {
                    int row = i * 2 + rbase;
                    hv[i] = __hip_atomic_load(&src[(size_t)(bc * 16 + row) * (H_ / 2) + kp],
                                              __ATOMIC_RELAXED, __HIP_MEMORY_SCOPE_AGENT);
                }
            }
#pragma unroll
            for (int i = 0; i < 8; ++i) {
                int row = i * 2 + rbase;
                *(uint32_t*)&h_s[row][2 * kp] = (uint32_t)hv[i];
            }
        }
        bar_lds();   // B: h_s visible

        f32x4 acc0 = {0.f, 0.f, 0.f, 0.f};
        f32x4 acc1 = {0.f, 0.f, 0.f, 0.f};
        if (t > 0) {
#pragma unroll
            for (int j = 0; j < 4; ++j) {
                s16x8 a  = *(const s16x8*)&h_s[mrow][(2 * j) * 32 + quad * 8];
                s16x8 bb = *(const s16x8*)&Wh_s[wave][mrow][(2 * j) * 32 + quad * 8];
                acc0 = __builtin_amdgcn_mfma_f32_16x16x32_bf16(a, bb, acc0, 0, 0, 0);
                s16x8 a2  = *(const s16x8*)&h_s[mrow][(2 * j + 1) * 32 + quad * 8];
                s16x8 bb2 = *(const s16x8*)&Wh_s[wave][mrow][(2 * j + 1) * 32 + quad * 8];
                acc1 = __builtin_amdgcn_mfma_f32_16x16x32_bf16(a2, bb2, acc1, 0, 0, 0);
            }
        }

#pragma unroll
        for (int r = 0; r < 4; ++r)
            pre_s[wave][quad * 4 + r][mrow] = accx[r] + acc0[r] + acc1[r];
        bar_lds();   // C: pre-activations ready

        float pg = pre_s[0][b_l][u_l] + bias_s[0][u_l];
        float pi = pre_s[1][b_l][u_l] + bias_s[1][u_l];
        float pf = pre_s[2][b_l][u_l] + bias_s[2][u_l];
        float po = pre_s[3][b_l][u_l] + bias_s[3][u_l];
        float gg = 2.0f * sigm(2.0f * pg) - 1.0f;   // tanh
        float ii = sigm(pi), ff = sigm(pf), oo = sigm(po);
        c_st = gg * ii + c_st * ff;
        float th = 2.0f * sigm(2.0f * c_st) - 1.0f; // tanh(c)
        h_st = th * oo;

        // publish: u64 = [tag t | 2 bf16], 128 stores/block
        uint32_t hb = f2bf(h_st);
        uint32_t p = hb | ((uint32_t)__shfl_down((int)hb, 1, 64) << 16);
        if ((tid & 1) == 0) {
            uint64_t val = (uint64_t)p | ((uint64_t)(uint32_t)t << 32);
            uint64_t* dst = hbuf + (size_t)(t & 1) * (B_ * (H_ / 2));
            __hip_atomic_store(&dst[(size_t)(bc * 16 + b_l) * (H_ / 2) + hc * 8 + (u_l >> 1)],
                               val, __ATOMIC_RELAXED, __HIP_MEMORY_SCOPE_AGENT);
        }
        // no drain: next iteration's lgkm-only barrier leaves stores in flight
    }

    // fused output projection: out[row][c] += sum_u h[row][u] * Wph[u][c] (+bias)
    {
        const int urow = hc * 16 + u_l;
        float wrow[C_];
#pragma unroll
        for (int c = 0; c < C_; ++c) wrow[c] = Wph[(size_t)urow * C_ + c];
#pragma unroll
        for (int c = 0; c < C_; ++c) {
            float v = h_st * wrow[c];
            v += __shfl_xor(v, 1, 64);
            v += __shfl_xor(v, 2, 64);
            v += __shfl_xor(v, 4, 64);
            v += __shfl_xor(v, 8, 64);
            if (u_l == 0) {
                if (hc == 0) v += bp[c];
                atomicAdd(&out[(size_t)(bc * 16 + b_l) * C_ + c], v);
            }
        }
    }
}

// ---------------------------------------------------------------------------
extern "C" void kernel_launch(void* const* d_in, const int* in_sizes, int n_in,
                              void* d_out, int out_size, void* d_ws, size_t ws_size,
                              hipStream_t stream) {
    const float* x   = (const float*)d_in[0];
    const float* Wgx = (const float*)d_in[1];
    const float* Wix = (const float*)d_in[2];
    const float* Wfx = (const float*)d_in[3];
    const float* Wox = (const float*)d_in[4];
    const float* Wgh = (const float*)d_in[5];
    const float* Wih = (const float*)d_in[6];
    const float* Wfh = (const float*)d_in[7];
    const float* Woh = (const float*)d_in[8];
    const float* bg  = (const float*)d_in[9];
    const float* bi  = (const float*)d_in[10];
    const float* bf2 = (const float*)d_in[11];
    const float* bo  = (const float*)d_in[12];
    const float* Wph = (const float*)d_in[13];
    const float* bp  = (const float*)d_in[14];

    char* ws = (char*)d_ws;
    uint64_t*       hbuf = (uint64_t*)ws;                              // 512 KiB
    unsigned short* xt   = (unsigned short*)(ws + 2 * B_ * (H_ / 2) * 8);

    hipMemsetAsync(d_out, 0, B_ * C_ * sizeof(float), stream);

    xt_kernel<<<B_ * (T_ / 64), 256, 0, stream>>>(x, xt);

    lstm_kernel<<<256, 256, 0, stream>>>(Wgx, Wix, Wfx, Wox, Wgh, Wih, Wfh, Woh,
                                         bg, bi, bf2, bo, xt, hbuf,
                                         Wph, bp, (float*)d_out);
}